// Round 4
// baseline (1695.675 us; speedup 1.0000x reference)
//
#include <hip/hip_runtime.h>

#define M_EDGES 150000
#define NN_NODES 50000
#define N_TRIS  100000
#define F 256
#define NLAYERS 4

typedef __attribute__((ext_vector_type(8))) __bf16 bf16x8;
typedef __attribute__((ext_vector_type(4))) float f32x4;

__device__ inline unsigned short f2bf(float f) {
    unsigned int u = __float_as_uint(f);
    u += 0x7fff + ((u >> 16) & 1);
    return (unsigned short)(u >> 16);
}
__device__ inline float bf2f(unsigned short h) {
    return __uint_as_float(((unsigned int)h) << 16);
}

__device__ inline void async16(const void* g, void* l) {
    __builtin_amdgcn_global_load_lds(
        (const __attribute__((address_space(1))) void*)g,
        (__attribute__((address_space(3))) void*)l, 16, 0, 0);
}

// ---------------------------------------------------------------------------
// bf16 MFMA GEMM: X (M x 256) @ WcatT^T  (WcatT: 768 x 256, n-major).
// Grid is 1-D over M; each block loops bn=0..5 internally so X is HBM-fetched
// once (later bn passes hit L2).  LDS uses XOR swizzle: physical 16B granule
// p = g ^ ((row>>1)&3)  -> fragment ds_read_b128 tiles all 32 banks 2-way.
//   bn 0,1 -> y0   2,3 -> y1   4,5 -> y2   (all bf16 stores)
// ---------------------------------------------------------------------------
__global__ __launch_bounds__(256) void gemm_mfma(
    const unsigned short* __restrict__ xb,
    const unsigned short* __restrict__ wt,
    unsigned short* __restrict__ y0,
    unsigned short* __restrict__ y1,
    unsigned short* __restrict__ y2)
{
    __shared__ unsigned short As[128 * 32];
    __shared__ unsigned short Bs[128 * 32];

    const int tid  = threadIdx.x;
    const int bm0  = blockIdx.x * 128;
    const int wid  = tid >> 6;
    const int lane = tid & 63;
    const int lm   = lane & 15;
    const int lh   = lane >> 4;
    const int wm   = wid >> 1;
    const int wn   = wid & 1;
    const int wbase = tid & ~63;

    for (int bn = 0; bn < 6; bn++) {
        f32x4 c[4][4];
#pragma unroll
        for (int i = 0; i < 4; i++)
#pragma unroll
            for (int j = 0; j < 4; j++) c[i][j] = (f32x4){0.f, 0.f, 0.f, 0.f};

        for (int k0 = 0; k0 < 256; k0 += 32) {
#pragma unroll
            for (int s = 0; s < 2; s++) {
                int i   = s * 256 + tid;        // slot = physical granule
                int row = i >> 2;
                int g   = (i & 3) ^ ((row >> 1) & 3);   // logical k-granule
                int gr  = bm0 + row;
                if (gr > M_EDGES - 1) gr = M_EDGES - 1;
                async16(xb + (size_t)gr * 256 + k0 + g * 8,
                        As + (size_t)(s * 256 + wbase) * 8);
                int nrow = bn * 128 + row;
                async16(wt + (size_t)nrow * 256 + k0 + g * 8,
                        Bs + (size_t)(s * 256 + wbase) * 8);
            }
            asm volatile("s_waitcnt vmcnt(0)" ::: "memory");
            __syncthreads();

            bf16x8 a[4], b[4];
#pragma unroll
            for (int i = 0; i < 4; i++) {
                int rr = wm * 64 + i * 16 + lm;
                a[i] = *(const bf16x8*)(As + rr * 32 + ((lh ^ ((rr >> 1) & 3)) * 8));
            }
#pragma unroll
            for (int j = 0; j < 4; j++) {
                int rr = wn * 64 + j * 16 + lm;
                b[j] = *(const bf16x8*)(Bs + rr * 32 + ((lh ^ ((rr >> 1) & 3)) * 8));
            }
#pragma unroll
            for (int i = 0; i < 4; i++)
#pragma unroll
                for (int j = 0; j < 4; j++)
                    c[i][j] = __builtin_amdgcn_mfma_f32_16x16x32_bf16(a[i], b[j], c[i][j], 0, 0, 0);
            __syncthreads();
        }

        const int seg = bn >> 1;
        unsigned short* dst = (seg == 0) ? y0 : (seg == 1) ? y1 : y2;
        const int colbase = (bn * 128 + wn * 64) & 255;
#pragma unroll
        for (int i = 0; i < 4; i++) {
#pragma unroll
            for (int r = 0; r < 4; r++) {
                int grow = bm0 + wm * 64 + i * 16 + lh * 4 + r;
                if (grow < M_EDGES) {
#pragma unroll
                    for (int j = 0; j < 4; j++) {
                        int col = colbase + j * 16 + lm;
                        dst[(size_t)grow * 256 + col] = f2bf(c[i][j][r]);
                    }
                }
            }
        }
    }
}

// ---------------------------------------------------------------------------
// CSR build
// ---------------------------------------------------------------------------
__global__ __launch_bounds__(256) void count_nodes(
    const int* __restrict__ en, int* __restrict__ cnt)
{
    int e = blockIdx.x * 256 + threadIdx.x;
    if (e < M_EDGES) {
        atomicAdd(&cnt[en[2 * e]], 1);
        atomicAdd(&cnt[en[2 * e + 1]], 1);
    }
}

__global__ __launch_bounds__(256) void count_tris(
    const int* __restrict__ te, int* __restrict__ cnt)
{
    int t = blockIdx.x * 256 + threadIdx.x;
    if (t < N_TRIS) {
#pragma unroll
        for (int k = 0; k < 3; k++) atomicAdd(&cnt[te[3 * t + k]], 1);
    }
}

__global__ __launch_bounds__(256) void scan_block(
    const int* __restrict__ cnt, int* __restrict__ off,
    int* __restrict__ partial, int n)
{
    __shared__ int s[256];
    int t = threadIdx.x;
    int gid = blockIdx.x * 256 + t;
    int v = (gid < n) ? cnt[gid] : 0;
    s[t] = v;
    __syncthreads();
    for (int o = 1; o < 256; o <<= 1) {
        int x = (t >= o) ? s[t - o] : 0;
        __syncthreads();
        s[t] += x;
        __syncthreads();
    }
    if (gid < n) off[gid] = s[t] - v;
    if (t == 255) partial[blockIdx.x] = s[255];
}

__global__ __launch_bounds__(1024) void scan_partial(int* __restrict__ partial, int nb)
{
    __shared__ int s[1024];
    int t = threadIdx.x;
    int v = (t < nb) ? partial[t] : 0;
    s[t] = v;
    __syncthreads();
    for (int o = 1; o < 1024; o <<= 1) {
        int x = (t >= o) ? s[t - o] : 0;
        __syncthreads();
        s[t] += x;
        __syncthreads();
    }
    if (t < nb) partial[t] = s[t] - v;
}

__global__ __launch_bounds__(256) void scan_add(
    int* __restrict__ off, int* __restrict__ cursor,
    const int* __restrict__ partial, int n, int total)
{
    int gid = blockIdx.x * 256 + threadIdx.x;
    if (gid == 0) off[n] = total;
    if (gid < n) {
        int o = off[gid] + partial[blockIdx.x];
        off[gid] = o;
        cursor[gid] = o;
    }
}

__global__ __launch_bounds__(256) void fill_nodes(
    const int* __restrict__ en, int* __restrict__ cursor, int* __restrict__ adj)
{
    int e = blockIdx.x * 256 + threadIdx.x;
    if (e < M_EDGES) {
        int u = en[2 * e], v = en[2 * e + 1];
        adj[atomicAdd(&cursor[u], 1)] = (e << 1);
        adj[atomicAdd(&cursor[v], 1)] = (e << 1) | 1;
    }
}

__global__ __launch_bounds__(256) void fill_tris(
    const int* __restrict__ te, const int* __restrict__ ts,
    int* __restrict__ cursor, int* __restrict__ adj)
{
    int t = blockIdx.x * 256 + threadIdx.x;
    if (t < N_TRIS) {
#pragma unroll
        for (int k = 0; k < 3; k++) {
            int e = te[3 * t + k];
            int neg = (ts[3 * t + k] < 0) ? 1 : 0;
            adj[atomicAdd(&cursor[e], 1)] = (t << 1) | neg;
        }
    }
}

// ---------------------------------------------------------------------------
// w[t] = sum_k s_k * y2[e_k]
// ---------------------------------------------------------------------------
__global__ __launch_bounds__(256) void w_tri(
    const unsigned short* __restrict__ y2,
    const int* __restrict__ te,
    const int* __restrict__ ts,
    unsigned short* __restrict__ w)
{
    int t = blockIdx.x * 4 + (threadIdx.x >> 6);
    int lane = threadIdx.x & 63;
    int e0 = te[3 * t + 0], e1 = te[3 * t + 1], e2 = te[3 * t + 2];
    float s0 = (float)ts[3 * t + 0];
    float s1 = (float)ts[3 * t + 1];
    float s2 = (float)ts[3 * t + 2];
    int f = lane * 4;
    ushort4 a4 = *(const ushort4*)(y2 + (size_t)e0 * 256 + f);
    ushort4 b4 = *(const ushort4*)(y2 + (size_t)e1 * 256 + f);
    ushort4 d4 = *(const ushort4*)(y2 + (size_t)e2 * 256 + f);
    ushort4 r;
    r.x = f2bf(s0 * bf2f(a4.x) + s1 * bf2f(b4.x) + s2 * bf2f(d4.x));
    r.y = f2bf(s0 * bf2f(a4.y) + s1 * bf2f(b4.y) + s2 * bf2f(d4.y));
    r.z = f2bf(s0 * bf2f(a4.z) + s1 * bf2f(b4.z) + s2 * bf2f(d4.z));
    r.w = f2bf(s0 * bf2f(a4.w) + s1 * bf2f(b4.w) + s2 * bf2f(d4.w));
    *(ushort4*)(w + (size_t)t * 256 + f) = r;
}

// ---------------------------------------------------------------------------
// z[n] = sum_{(e,dir)} (+/-) y0[e]   (bf16 out)
// ---------------------------------------------------------------------------
__global__ __launch_bounds__(256) void z_node(
    const unsigned short* __restrict__ y0,
    const int* __restrict__ noff,
    const int* __restrict__ nadj,
    unsigned short* __restrict__ z)
{
    int n = blockIdx.x * 4 + (threadIdx.x >> 6);
    int lane = threadIdx.x & 63;
    int f = lane * 4;
    int beg = noff[n], end = noff[n + 1];
    float ax = 0.f, ay = 0.f, az = 0.f, aw = 0.f;
    for (int i = beg; i < end; i++) {
        int ent = nadj[i];
        int e = ent >> 1;
        float sg = (ent & 1) ? 1.f : -1.f;
        ushort4 yv = *(const ushort4*)(y0 + (size_t)e * 256 + f);
        ax += sg * bf2f(yv.x);
        ay += sg * bf2f(yv.y);
        az += sg * bf2f(yv.z);
        aw += sg * bf2f(yv.w);
    }
    ushort4 r;
    r.x = f2bf(ax); r.y = f2bf(ay); r.z = f2bf(az); r.w = f2bf(aw);
    *(ushort4*)(z + (size_t)n * 256 + f) = r;
}

// ---------------------------------------------------------------------------
// x_next[e] = relu( y1[e] + sum s*w[t] + z[v]-z[u] )
// ---------------------------------------------------------------------------
__global__ __launch_bounds__(256) void relu_fused(
    const unsigned short* __restrict__ y1,
    const unsigned short* __restrict__ w,
    const unsigned short* __restrict__ z,
    const int* __restrict__ en,
    const int* __restrict__ eoff,
    const int* __restrict__ eadj,
    unsigned short* __restrict__ xb)
{
    int e = blockIdx.x * 4 + (threadIdx.x >> 6);
    int lane = threadIdx.x & 63;
    int f = lane * 4;
    ushort4 a4 = *(const ushort4*)(y1 + (size_t)e * 256 + f);
    float sx = bf2f(a4.x), sy = bf2f(a4.y), sz = bf2f(a4.z), sw = bf2f(a4.w);
    int beg = eoff[e], end = eoff[e + 1];
    for (int i = beg; i < end; i++) {
        int ent = eadj[i];
        int t = ent >> 1;
        float sg = (ent & 1) ? -1.f : 1.f;
        ushort4 wv = *(const ushort4*)(w + (size_t)t * 256 + f);
        sx += sg * bf2f(wv.x);
        sy += sg * bf2f(wv.y);
        sz += sg * bf2f(wv.z);
        sw += sg * bf2f(wv.w);
    }
    int u = en[2 * e], v = en[2 * e + 1];
    ushort4 zv = *(const ushort4*)(z + (size_t)v * 256 + f);
    ushort4 zu = *(const ushort4*)(z + (size_t)u * 256 + f);
    ushort4 r;
    r.x = f2bf(fmaxf(sx + bf2f(zv.x) - bf2f(zu.x), 0.f));
    r.y = f2bf(fmaxf(sy + bf2f(zv.y) - bf2f(zu.y), 0.f));
    r.z = f2bf(fmaxf(sz + bf2f(zv.z) - bf2f(zu.z), 0.f));
    r.w = f2bf(fmaxf(sw + bf2f(zv.w) - bf2f(zu.w), 0.f));
    *(ushort4*)(xb + (size_t)e * 256 + f) = r;
}

// ---------------------------------------------------------------------------
// p[e] = x[e] . W0_L ; out[n] = sum (+/-) p[e]
// ---------------------------------------------------------------------------
__global__ __launch_bounds__(256) void dotp(
    const unsigned short* __restrict__ xb,
    const float* __restrict__ wl,
    float* __restrict__ p)
{
    int e = blockIdx.x * 4 + (threadIdx.x >> 6);
    int lane = threadIdx.x & 63;
    ushort4 xv = *(const ushort4*)(xb + (size_t)e * 256 + lane * 4);
    float4 wv = *(const float4*)(wl + lane * 4);
    float s = bf2f(xv.x) * wv.x + bf2f(xv.y) * wv.y +
              bf2f(xv.z) * wv.z + bf2f(xv.w) * wv.w;
#pragma unroll
    for (int off = 32; off > 0; off >>= 1)
        s += __shfl_down(s, off, 64);
    if (lane == 0) p[e] = s;
}

__global__ __launch_bounds__(256) void out_nodes(
    const float* __restrict__ p,
    const int* __restrict__ noff,
    const int* __restrict__ nadj,
    float* __restrict__ out)
{
    int n = blockIdx.x * 256 + threadIdx.x;
    if (n >= NN_NODES) return;
    int beg = noff[n], end = noff[n + 1];
    float s = 0.f;
    for (int i = beg; i < end; i++) {
        int ent = nadj[i];
        float sg = (ent & 1) ? 1.f : -1.f;
        s += sg * p[ent >> 1];
    }
    out[n] = s;
}

// ---------------------------------------------------------------------------
// Conversions
// ---------------------------------------------------------------------------
__global__ __launch_bounds__(256) void cvt_x(
    const float* __restrict__ x, unsigned short* __restrict__ xb)
{
    int idx = blockIdx.x * 256 + threadIdx.x;
    float4 v = *(const float4*)(x + (size_t)idx * 4);
    ushort4 r;
    r.x = f2bf(v.x); r.y = f2bf(v.y); r.z = f2bf(v.z); r.w = f2bf(v.w);
    *(ushort4*)(xb + (size_t)idx * 4) = r;
}

__global__ __launch_bounds__(256) void cvt_w(
    const float* __restrict__ W0, const float* __restrict__ W1,
    const float* __restrict__ W2, unsigned short* __restrict__ wt)
{
    int idx = blockIdx.x * 256 + threadIdx.x;
    int l = idx / (768 * 256);
    int rem = idx - l * (768 * 256);
    int n = rem >> 8;
    int k = rem & 255;
    const float* src;
    int nn;
    if (n < 256)      { src = W0; nn = n; }
    else if (n < 512) { src = W1; nn = n - 256; }
    else              { src = W2; nn = n - 512; }
    wt[idx] = f2bf(src[(size_t)l * 65536 + k * 256 + nn]);
}

extern "C" void kernel_launch(void* const* d_in, const int* in_sizes, int n_in,
                              void* d_out, int out_size, void* d_ws, size_t ws_size,
                              hipStream_t stream)
{
    const float* x0  = (const float*)d_in[0];
    const float* W0s = (const float*)d_in[1];
    const float* W1s = (const float*)d_in[2];
    const float* W2s = (const float*)d_in[3];
    const float* WL  = (const float*)d_in[4];
    const int*   en  = (const int*)d_in[5];
    const int*   te  = (const int*)d_in[6];
    const int*   ts  = (const int*)d_in[7];
    float* out = (float*)d_out;

    const size_t MF = (size_t)M_EDGES * F;
    unsigned short* xb = (unsigned short*)d_ws;        // MF
    unsigned short* y0 = xb + MF;                      // MF
    unsigned short* y1 = y0 + MF;                      // MF
    unsigned short* y2 = y1 + MF;                      // MF
    unsigned short* wt = y2 + MF;                      // 4*768*256
    unsigned short* wb = wt + (size_t)4 * 768 * 256;   // N_TRIS*256
    unsigned short* zb = wb + (size_t)N_TRIS * 256;    // NN*256 bf16
    float* p = (float*)(zb + (size_t)NN_NODES * 256);  // M f32
    int* noff = (int*)(p + M_EDGES);                   // NN+1
    int* ncur = noff + (NN_NODES + 1);                 // NN
    int* nadj = ncur + NN_NODES;                       // 2*M
    int* eoff = nadj + 2 * M_EDGES;                    // M+1
    int* ecur = eoff + (M_EDGES + 1);                  // M
    int* eadj = ecur + M_EDGES;                        // 3*N_TRIS
    int* part = eadj + 3 * N_TRIS;                     // 1024

    cvt_w<<<(4 * 768 * 256) / 256, 256, 0, stream>>>(W0s, W1s, W2s, wt);
    cvt_x<<<(int)(MF / 4 / 256), 256, 0, stream>>>(x0, xb);

    const int nbN = (NN_NODES + 255) / 256;
    const int nbE = (M_EDGES + 255) / 256;
    hipMemsetAsync(ncur, 0, NN_NODES * sizeof(int), stream);
    hipMemsetAsync(ecur, 0, M_EDGES * sizeof(int), stream);
    count_nodes<<<nbE, 256, 0, stream>>>(en, ncur);
    count_tris<<<(N_TRIS + 255) / 256, 256, 0, stream>>>(te, ecur);
    scan_block<<<nbN, 256, 0, stream>>>(ncur, noff, part, NN_NODES);
    scan_partial<<<1, 1024, 0, stream>>>(part, nbN);
    scan_add<<<nbN, 256, 0, stream>>>(noff, ncur, part, NN_NODES, 2 * M_EDGES);
    fill_nodes<<<nbE, 256, 0, stream>>>(en, ncur, nadj);
    scan_block<<<nbE, 256, 0, stream>>>(ecur, eoff, part, M_EDGES);
    scan_partial<<<1, 1024, 0, stream>>>(part, nbE);
    scan_add<<<nbE, 256, 0, stream>>>(eoff, ecur, part, M_EDGES, 3 * N_TRIS);
    fill_tris<<<(N_TRIS + 255) / 256, 256, 0, stream>>>(te, ts, ecur, eadj);

    dim3 ggrid((M_EDGES + 127) / 128);
    for (int l = 0; l < NLAYERS; l++) {
        gemm_mfma<<<ggrid, 256, 0, stream>>>(
            xb, wt + (size_t)l * 768 * 256, y0, y1, y2);
        w_tri<<<N_TRIS / 4, 256, 0, stream>>>(y2, te, ts, wb);
        z_node<<<NN_NODES / 4, 256, 0, stream>>>(y0, noff, nadj, zb);
        relu_fused<<<M_EDGES / 4, 256, 0, stream>>>(y1, wb, zb, en, eoff, eadj, xb);
    }

    dotp<<<M_EDGES / 4, 256, 0, stream>>>(xb, WL, p);
    out_nodes<<<(NN_NODES + 255) / 256, 256, 0, stream>>>(p, noff, nadj, out);
}

// Round 5
// 1472.354 us; speedup vs baseline: 1.1517x; 1.1517x over previous
//
#include <hip/hip_runtime.h>

#define M_EDGES 150000
#define NN_NODES 50000
#define N_TRIS  100000
#define F 256
#define NLAYERS 4

typedef __attribute__((ext_vector_type(8))) __bf16 bf16x8;
typedef __attribute__((ext_vector_type(4))) float f32x4;

__device__ inline unsigned short f2bf(float f) {
    unsigned int u = __float_as_uint(f);
    u += 0x7fff + ((u >> 16) & 1);
    return (unsigned short)(u >> 16);
}
__device__ inline float bf2f(unsigned short h) {
    return __uint_as_float(((unsigned int)h) << 16);
}

__device__ inline void async16(const void* g, void* l) {
    __builtin_amdgcn_global_load_lds(
        (const __attribute__((address_space(1))) void*)g,
        (__attribute__((address_space(3))) void*)l, 16, 0, 0);
}

// ---------------------------------------------------------------------------
// bf16 MFMA GEMM: X (M x 256) @ WcatT^T (WcatT: 768 x 256, n-major).
// grid = (6, 1172): blockIdx.x = bn (FASTEST) so the 6 blocks sharing an
// X row-tile dispatch together -> cross-XCD L2/L3 temporal locality.
// XOR-swizzled LDS (bank-conflict-free fragment reads, verified r4: 7.2M->0).
//   bn 0,1 -> y0   2,3 -> y1   4,5 -> y2   (bf16 stores)
// ---------------------------------------------------------------------------
__global__ __launch_bounds__(256) void gemm_mfma(
    const unsigned short* __restrict__ xb,
    const unsigned short* __restrict__ wt,
    unsigned short* __restrict__ y0,
    unsigned short* __restrict__ y1,
    unsigned short* __restrict__ y2)
{
    __shared__ unsigned short As[128 * 32];
    __shared__ unsigned short Bs[128 * 32];

    const int tid  = threadIdx.x;
    const int bn   = blockIdx.x;
    const int bm0  = blockIdx.y * 128;
    const int wid  = tid >> 6;
    const int lane = tid & 63;
    const int lm   = lane & 15;
    const int lh   = lane >> 4;
    const int wm   = wid >> 1;
    const int wn   = wid & 1;
    const int wbase = tid & ~63;

    f32x4 c[4][4];
#pragma unroll
    for (int i = 0; i < 4; i++)
#pragma unroll
        for (int j = 0; j < 4; j++) c[i][j] = (f32x4){0.f, 0.f, 0.f, 0.f};

    for (int k0 = 0; k0 < 256; k0 += 32) {
#pragma unroll
        for (int s = 0; s < 2; s++) {
            int i   = s * 256 + tid;                 // slot = physical granule
            int row = i >> 2;
            int g   = (i & 3) ^ ((row >> 1) & 3);    // logical k-granule
            int gr  = bm0 + row;
            if (gr > M_EDGES - 1) gr = M_EDGES - 1;
            async16(xb + (size_t)gr * 256 + k0 + g * 8,
                    As + (size_t)(s * 256 + wbase) * 8);
            int nrow = bn * 128 + row;
            async16(wt + (size_t)nrow * 256 + k0 + g * 8,
                    Bs + (size_t)(s * 256 + wbase) * 8);
        }
        asm volatile("s_waitcnt vmcnt(0)" ::: "memory");
        __syncthreads();

        bf16x8 a[4], b[4];
#pragma unroll
        for (int i = 0; i < 4; i++) {
            int rr = wm * 64 + i * 16 + lm;
            a[i] = *(const bf16x8*)(As + rr * 32 + ((lh ^ ((rr >> 1) & 3)) * 8));
        }
#pragma unroll
        for (int j = 0; j < 4; j++) {
            int rr = wn * 64 + j * 16 + lm;
            b[j] = *(const bf16x8*)(Bs + rr * 32 + ((lh ^ ((rr >> 1) & 3)) * 8));
        }
#pragma unroll
        for (int i = 0; i < 4; i++)
#pragma unroll
            for (int j = 0; j < 4; j++)
                c[i][j] = __builtin_amdgcn_mfma_f32_16x16x32_bf16(a[i], b[j], c[i][j], 0, 0, 0);
        __syncthreads();
    }

    const int seg = bn >> 1;
    unsigned short* dst = (seg == 0) ? y0 : (seg == 1) ? y1 : y2;
    const int colbase = (bn * 128 + wn * 64) & 255;
#pragma unroll
    for (int i = 0; i < 4; i++) {
#pragma unroll
        for (int r = 0; r < 4; r++) {
            int grow = bm0 + wm * 64 + i * 16 + lh * 4 + r;
            if (grow < M_EDGES) {
#pragma unroll
                for (int j = 0; j < 4; j++) {
                    int col = colbase + j * 16 + lm;
                    dst[(size_t)grow * 256 + col] = f2bf(c[i][j][r]);
                }
            }
        }
    }
}

// ---------------------------------------------------------------------------
// CSR build
// ---------------------------------------------------------------------------
__global__ __launch_bounds__(256) void count_nodes(
    const int* __restrict__ en, int* __restrict__ cnt)
{
    int e = blockIdx.x * 256 + threadIdx.x;
    if (e < M_EDGES) {
        atomicAdd(&cnt[en[2 * e]], 1);
        atomicAdd(&cnt[en[2 * e + 1]], 1);
    }
}

__global__ __launch_bounds__(256) void count_tris(
    const int* __restrict__ te, int* __restrict__ cnt)
{
    int t = blockIdx.x * 256 + threadIdx.x;
    if (t < N_TRIS) {
#pragma unroll
        for (int k = 0; k < 3; k++) atomicAdd(&cnt[te[3 * t + k]], 1);
    }
}

__global__ __launch_bounds__(256) void scan_block(
    const int* __restrict__ cnt, int* __restrict__ off,
    int* __restrict__ partial, int n)
{
    __shared__ int s[256];
    int t = threadIdx.x;
    int gid = blockIdx.x * 256 + t;
    int v = (gid < n) ? cnt[gid] : 0;
    s[t] = v;
    __syncthreads();
    for (int o = 1; o < 256; o <<= 1) {
        int x = (t >= o) ? s[t - o] : 0;
        __syncthreads();
        s[t] += x;
        __syncthreads();
    }
    if (gid < n) off[gid] = s[t] - v;
    if (t == 255) partial[blockIdx.x] = s[255];
}

__global__ __launch_bounds__(1024) void scan_partial(int* __restrict__ partial, int nb)
{
    __shared__ int s[1024];
    int t = threadIdx.x;
    int v = (t < nb) ? partial[t] : 0;
    s[t] = v;
    __syncthreads();
    for (int o = 1; o < 1024; o <<= 1) {
        int x = (t >= o) ? s[t - o] : 0;
        __syncthreads();
        s[t] += x;
        __syncthreads();
    }
    if (t < nb) partial[t] = s[t] - v;
}

__global__ __launch_bounds__(256) void scan_add(
    int* __restrict__ off, int* __restrict__ cursor,
    const int* __restrict__ partial, int n, int total)
{
    int gid = blockIdx.x * 256 + threadIdx.x;
    if (gid == 0) off[n] = total;
    if (gid < n) {
        int o = off[gid] + partial[blockIdx.x];
        off[gid] = o;
        cursor[gid] = o;
    }
}

__global__ __launch_bounds__(256) void fill_nodes(
    const int* __restrict__ en, int* __restrict__ cursor, int* __restrict__ adj)
{
    int e = blockIdx.x * 256 + threadIdx.x;
    if (e < M_EDGES) {
        int u = en[2 * e], v = en[2 * e + 1];
        adj[atomicAdd(&cursor[u], 1)] = (e << 1);
        adj[atomicAdd(&cursor[v], 1)] = (e << 1) | 1;
    }
}

__global__ __launch_bounds__(256) void fill_tris(
    const int* __restrict__ te, const int* __restrict__ ts,
    int* __restrict__ cursor, int* __restrict__ adj)
{
    int t = blockIdx.x * 256 + threadIdx.x;
    if (t < N_TRIS) {
#pragma unroll
        for (int k = 0; k < 3; k++) {
            int e = te[3 * t + k];
            int neg = (ts[3 * t + k] < 0) ? 1 : 0;
            adj[atomicAdd(&cursor[e], 1)] = (t << 1) | neg;
        }
    }
}

// ---------------------------------------------------------------------------
// Fused gather pass A:
//   blocks [0, N_TRIS/4)          : w[t] = sum_k s_k * y2[e_k]
//   blocks [N_TRIS/4, +NN/4)      : z[n] = sum (+/-) y0[e]   (bf16 out)
// ---------------------------------------------------------------------------
#define WT_BLOCKS (N_TRIS / 4)
#define ZN_BLOCKS (NN_NODES / 4)

__global__ __launch_bounds__(256) void zw_fused(
    const unsigned short* __restrict__ y2,
    const int* __restrict__ te,
    const int* __restrict__ ts,
    unsigned short* __restrict__ w,
    const unsigned short* __restrict__ y0,
    const int* __restrict__ noff,
    const int* __restrict__ nadj,
    unsigned short* __restrict__ z)
{
    int lane = threadIdx.x & 63;
    int f = lane * 4;
    if (blockIdx.x < WT_BLOCKS) {
        int t = blockIdx.x * 4 + (threadIdx.x >> 6);
        int e0 = te[3 * t + 0], e1 = te[3 * t + 1], e2 = te[3 * t + 2];
        float s0 = (float)ts[3 * t + 0];
        float s1 = (float)ts[3 * t + 1];
        float s2 = (float)ts[3 * t + 2];
        ushort4 a4 = *(const ushort4*)(y2 + (size_t)e0 * 256 + f);
        ushort4 b4 = *(const ushort4*)(y2 + (size_t)e1 * 256 + f);
        ushort4 d4 = *(const ushort4*)(y2 + (size_t)e2 * 256 + f);
        ushort4 r;
        r.x = f2bf(s0 * bf2f(a4.x) + s1 * bf2f(b4.x) + s2 * bf2f(d4.x));
        r.y = f2bf(s0 * bf2f(a4.y) + s1 * bf2f(b4.y) + s2 * bf2f(d4.y));
        r.z = f2bf(s0 * bf2f(a4.z) + s1 * bf2f(b4.z) + s2 * bf2f(d4.z));
        r.w = f2bf(s0 * bf2f(a4.w) + s1 * bf2f(b4.w) + s2 * bf2f(d4.w));
        *(ushort4*)(w + (size_t)t * 256 + f) = r;
    } else {
        int n = (blockIdx.x - WT_BLOCKS) * 4 + (threadIdx.x >> 6);
        int beg = noff[n], end = noff[n + 1];
        float ax = 0.f, ay = 0.f, az = 0.f, aw = 0.f;
        int i = beg;
        for (; i + 1 < end; i += 2) {
            int ea = nadj[i], eb = nadj[i + 1];
            float sa = (ea & 1) ? 1.f : -1.f;
            float sb = (eb & 1) ? 1.f : -1.f;
            ushort4 va = *(const ushort4*)(y0 + (size_t)(ea >> 1) * 256 + f);
            ushort4 vb = *(const ushort4*)(y0 + (size_t)(eb >> 1) * 256 + f);
            ax += sa * bf2f(va.x) + sb * bf2f(vb.x);
            ay += sa * bf2f(va.y) + sb * bf2f(vb.y);
            az += sa * bf2f(va.z) + sb * bf2f(vb.z);
            aw += sa * bf2f(va.w) + sb * bf2f(vb.w);
        }
        if (i < end) {
            int ea = nadj[i];
            float sa = (ea & 1) ? 1.f : -1.f;
            ushort4 va = *(const ushort4*)(y0 + (size_t)(ea >> 1) * 256 + f);
            ax += sa * bf2f(va.x);
            ay += sa * bf2f(va.y);
            az += sa * bf2f(va.z);
            aw += sa * bf2f(va.w);
        }
        ushort4 r;
        r.x = f2bf(ax); r.y = f2bf(ay); r.z = f2bf(az); r.w = f2bf(aw);
        *(ushort4*)(z + (size_t)n * 256 + f) = r;
    }
}

// ---------------------------------------------------------------------------
// x_next[e] = relu( y1[e] + sum s*w[t] + z[v]-z[u] )
// Early-issue y1/z loads; 2-wide strip over the tri adjacency for ILP.
// ---------------------------------------------------------------------------
__global__ __launch_bounds__(256) void relu_fused(
    const unsigned short* __restrict__ y1,
    const unsigned short* __restrict__ w,
    const unsigned short* __restrict__ z,
    const int* __restrict__ en,
    const int* __restrict__ eoff,
    const int* __restrict__ eadj,
    unsigned short* __restrict__ xb)
{
    int e = blockIdx.x * 4 + (threadIdx.x >> 6);
    int lane = threadIdx.x & 63;
    int f = lane * 4;
    int u = en[2 * e], v = en[2 * e + 1];
    int beg = eoff[e], end = eoff[e + 1];
    ushort4 a4 = *(const ushort4*)(y1 + (size_t)e * 256 + f);
    ushort4 zv = *(const ushort4*)(z + (size_t)v * 256 + f);
    ushort4 zu = *(const ushort4*)(z + (size_t)u * 256 + f);
    float sx = bf2f(a4.x) + bf2f(zv.x) - bf2f(zu.x);
    float sy = bf2f(a4.y) + bf2f(zv.y) - bf2f(zu.y);
    float sz = bf2f(a4.z) + bf2f(zv.z) - bf2f(zu.z);
    float sw = bf2f(a4.w) + bf2f(zv.w) - bf2f(zu.w);
    int i = beg;
    for (; i + 1 < end; i += 2) {
        int ta = eadj[i], tb = eadj[i + 1];
        float sa = (ta & 1) ? -1.f : 1.f;
        float sb = (tb & 1) ? -1.f : 1.f;
        ushort4 wa = *(const ushort4*)(w + (size_t)(ta >> 1) * 256 + f);
        ushort4 wbv = *(const ushort4*)(w + (size_t)(tb >> 1) * 256 + f);
        sx += sa * bf2f(wa.x) + sb * bf2f(wbv.x);
        sy += sa * bf2f(wa.y) + sb * bf2f(wbv.y);
        sz += sa * bf2f(wa.z) + sb * bf2f(wbv.z);
        sw += sa * bf2f(wa.w) + sb * bf2f(wbv.w);
    }
    if (i < end) {
        int ta = eadj[i];
        float sa = (ta & 1) ? -1.f : 1.f;
        ushort4 wa = *(const ushort4*)(w + (size_t)(ta >> 1) * 256 + f);
        sx += sa * bf2f(wa.x);
        sy += sa * bf2f(wa.y);
        sz += sa * bf2f(wa.z);
        sw += sa * bf2f(wa.w);
    }
    ushort4 r;
    r.x = f2bf(fmaxf(sx, 0.f));
    r.y = f2bf(fmaxf(sy, 0.f));
    r.z = f2bf(fmaxf(sz, 0.f));
    r.w = f2bf(fmaxf(sw, 0.f));
    *(ushort4*)(xb + (size_t)e * 256 + f) = r;
}

// ---------------------------------------------------------------------------
// p[e] = x[e] . W0_L ; out[n] = sum (+/-) p[e]
// ---------------------------------------------------------------------------
__global__ __launch_bounds__(256) void dotp(
    const unsigned short* __restrict__ xb,
    const float* __restrict__ wl,
    float* __restrict__ p)
{
    int e = blockIdx.x * 4 + (threadIdx.x >> 6);
    int lane = threadIdx.x & 63;
    ushort4 xv = *(const ushort4*)(xb + (size_t)e * 256 + lane * 4);
    float4 wv = *(const float4*)(wl + lane * 4);
    float s = bf2f(xv.x) * wv.x + bf2f(xv.y) * wv.y +
              bf2f(xv.z) * wv.z + bf2f(xv.w) * wv.w;
#pragma unroll
    for (int off = 32; off > 0; off >>= 1)
        s += __shfl_down(s, off, 64);
    if (lane == 0) p[e] = s;
}

__global__ __launch_bounds__(256) void out_nodes(
    const float* __restrict__ p,
    const int* __restrict__ noff,
    const int* __restrict__ nadj,
    float* __restrict__ out)
{
    int n = blockIdx.x * 256 + threadIdx.x;
    if (n >= NN_NODES) return;
    int beg = noff[n], end = noff[n + 1];
    float s = 0.f;
    for (int i = beg; i < end; i++) {
        int ent = nadj[i];
        float sg = (ent & 1) ? 1.f : -1.f;
        s += sg * p[ent >> 1];
    }
    out[n] = s;
}

// ---------------------------------------------------------------------------
// Conversions
// ---------------------------------------------------------------------------
__global__ __launch_bounds__(256) void cvt_x(
    const float* __restrict__ x, unsigned short* __restrict__ xb)
{
    int idx = blockIdx.x * 256 + threadIdx.x;
    float4 v = *(const float4*)(x + (size_t)idx * 4);
    ushort4 r;
    r.x = f2bf(v.x); r.y = f2bf(v.y); r.z = f2bf(v.z); r.w = f2bf(v.w);
    *(ushort4*)(xb + (size_t)idx * 4) = r;
}

__global__ __launch_bounds__(256) void cvt_w(
    const float* __restrict__ W0, const float* __restrict__ W1,
    const float* __restrict__ W2, unsigned short* __restrict__ wt)
{
    int idx = blockIdx.x * 256 + threadIdx.x;
    int l = idx / (768 * 256);
    int rem = idx - l * (768 * 256);
    int n = rem >> 8;
    int k = rem & 255;
    const float* src;
    int nn;
    if (n < 256)      { src = W0; nn = n; }
    else if (n < 512) { src = W1; nn = n - 256; }
    else              { src = W2; nn = n - 512; }
    wt[idx] = f2bf(src[(size_t)l * 65536 + k * 256 + nn]);
}

extern "C" void kernel_launch(void* const* d_in, const int* in_sizes, int n_in,
                              void* d_out, int out_size, void* d_ws, size_t ws_size,
                              hipStream_t stream)
{
    const float* x0  = (const float*)d_in[0];
    const float* W0s = (const float*)d_in[1];
    const float* W1s = (const float*)d_in[2];
    const float* W2s = (const float*)d_in[3];
    const float* WL  = (const float*)d_in[4];
    const int*   en  = (const int*)d_in[5];
    const int*   te  = (const int*)d_in[6];
    const int*   ts  = (const int*)d_in[7];
    float* out = (float*)d_out;

    const size_t MF = (size_t)M_EDGES * F;
    unsigned short* xb = (unsigned short*)d_ws;        // MF
    unsigned short* y0 = xb + MF;                      // MF
    unsigned short* y1 = y0 + MF;                      // MF
    unsigned short* y2 = y1 + MF;                      // MF
    unsigned short* wt = y2 + MF;                      // 4*768*256
    unsigned short* wb = wt + (size_t)4 * 768 * 256;   // N_TRIS*256
    unsigned short* zb = wb + (size_t)N_TRIS * 256;    // NN*256
    float* p = (float*)(zb + (size_t)NN_NODES * 256);  // M f32
    int* noff = (int*)(p + M_EDGES);                   // NN+1
    int* ncur = noff + (NN_NODES + 1);                 // NN
    int* nadj = ncur + NN_NODES;                       // 2*M
    int* eoff = nadj + 2 * M_EDGES;                    // M+1
    int* ecur = eoff + (M_EDGES + 1);                  // M
    int* eadj = ecur + M_EDGES;                        // 3*N_TRIS
    int* part = eadj + 3 * N_TRIS;                     // 1024

    cvt_w<<<(4 * 768 * 256) / 256, 256, 0, stream>>>(W0s, W1s, W2s, wt);
    cvt_x<<<(int)(MF / 4 / 256), 256, 0, stream>>>(x0, xb);

    const int nbN = (NN_NODES + 255) / 256;
    const int nbE = (M_EDGES + 255) / 256;
    hipMemsetAsync(ncur, 0, NN_NODES * sizeof(int), stream);
    hipMemsetAsync(ecur, 0, M_EDGES * sizeof(int), stream);
    count_nodes<<<nbE, 256, 0, stream>>>(en, ncur);
    count_tris<<<(N_TRIS + 255) / 256, 256, 0, stream>>>(te, ecur);
    scan_block<<<nbN, 256, 0, stream>>>(ncur, noff, part, NN_NODES);
    scan_partial<<<1, 1024, 0, stream>>>(part, nbN);
    scan_add<<<nbN, 256, 0, stream>>>(noff, ncur, part, NN_NODES, 2 * M_EDGES);
    fill_nodes<<<nbE, 256, 0, stream>>>(en, ncur, nadj);
    scan_block<<<nbE, 256, 0, stream>>>(ecur, eoff, part, M_EDGES);
    scan_partial<<<1, 1024, 0, stream>>>(part, nbE);
    scan_add<<<nbE, 256, 0, stream>>>(eoff, ecur, part, M_EDGES, 3 * N_TRIS);
    fill_tris<<<(N_TRIS + 255) / 256, 256, 0, stream>>>(te, ts, ecur, eadj);

    dim3 ggrid(6, (M_EDGES + 127) / 128);   // bn fastest
    for (int l = 0; l < NLAYERS; l++) {
        gemm_mfma<<<ggrid, 256, 0, stream>>>(
            xb, wt + (size_t)l * 768 * 256, y0, y1, y2);
        zw_fused<<<WT_BLOCKS + ZN_BLOCKS, 256, 0, stream>>>(
            y2, te, ts, wb, y0, noff, nadj, zb);
        relu_fused<<<M_EDGES / 4, 256, 0, stream>>>(y1, wb, zb, en, eoff, eadj, xb);
    }

    dotp<<<M_EDGES / 4, 256, 0, stream>>>(xb, WL, p);
    out_nodes<<<(NN_NODES + 255) / 256, 256, 0, stream>>>(p, noff, nadj, out);
}

// Round 6
// 1428.287 us; speedup vs baseline: 1.1872x; 1.0309x over previous
//
#include <hip/hip_runtime.h>

#define M_EDGES 150000
#define NN_NODES 50000
#define N_TRIS  100000
#define F 256
#define NLAYERS 4
#define NBM 1172                 // ceil(150000/128)
#define NBM_PAD 1176             // 8 * ceil(NBM/8)

typedef __attribute__((ext_vector_type(8))) __bf16 bf16x8;
typedef __attribute__((ext_vector_type(4))) float f32x4;

__device__ inline unsigned short f2bf(float f) {
    unsigned int u = __float_as_uint(f);
    u += 0x7fff + ((u >> 16) & 1);
    return (unsigned short)(u >> 16);
}
__device__ inline float bf2f(unsigned short h) {
    return __uint_as_float(((unsigned int)h) << 16);
}

__device__ inline void async16(const void* g, void* l) {
    __builtin_amdgcn_global_load_lds(
        (const __attribute__((address_space(1))) void*)g,
        (__attribute__((address_space(3))) void*)l, 16, 0, 0);
}

// ---------------------------------------------------------------------------
// bf16 MFMA GEMM: X (M x 256) @ WcatT^T (WcatT: 768 x 256, n-major).
// XCD-aware swizzle: xcd = b&7, c = b>>3, bm = (c/6)*8 + xcd, bn = c%6.
// All 6 bn-blocks of one bm share b%8 -> same XCD L2 -> X fetched from HBM
// once per bm (r5 showed bn-fastest WITHOUT xcd pinning leaves FETCH at 227MB).
// XOR-swizzled LDS (bank-conflict-free, verified r4: 7.2M -> 0).
//   bn 0,1 -> y0   2,3 -> y1   4,5 -> y2   (bf16 stores)
// ---------------------------------------------------------------------------
__global__ __launch_bounds__(256) void gemm_mfma(
    const unsigned short* __restrict__ xb,
    const unsigned short* __restrict__ wt,
    unsigned short* __restrict__ y0,
    unsigned short* __restrict__ y1,
    unsigned short* __restrict__ y2)
{
    __shared__ unsigned short As[128 * 32];
    __shared__ unsigned short Bs[128 * 32];

    const int b   = blockIdx.x;
    const int xcd = b & 7;
    const int c   = b >> 3;
    const int bm  = (c / 6) * 8 + xcd;
    const int bn  = c % 6;
    if (bm >= NBM) return;

    const int tid  = threadIdx.x;
    const int bm0  = bm * 128;
    const int wid  = tid >> 6;
    const int lane = tid & 63;
    const int lm   = lane & 15;
    const int lh   = lane >> 4;
    const int wm   = wid >> 1;
    const int wn   = wid & 1;
    const int wbase = tid & ~63;

    f32x4 cacc[4][4];
#pragma unroll
    for (int i = 0; i < 4; i++)
#pragma unroll
        for (int j = 0; j < 4; j++) cacc[i][j] = (f32x4){0.f, 0.f, 0.f, 0.f};

    for (int k0 = 0; k0 < 256; k0 += 32) {
#pragma unroll
        for (int s = 0; s < 2; s++) {
            int i   = s * 256 + tid;                 // slot = physical granule
            int row = i >> 2;
            int g   = (i & 3) ^ ((row >> 1) & 3);    // logical k-granule
            int gr  = bm0 + row;
            if (gr > M_EDGES - 1) gr = M_EDGES - 1;
            async16(xb + (size_t)gr * 256 + k0 + g * 8,
                    As + (size_t)(s * 256 + wbase) * 8);
            int nrow = bn * 128 + row;
            async16(wt + (size_t)nrow * 256 + k0 + g * 8,
                    Bs + (size_t)(s * 256 + wbase) * 8);
        }
        asm volatile("s_waitcnt vmcnt(0)" ::: "memory");
        __syncthreads();

        bf16x8 a[4], bfr[4];
#pragma unroll
        for (int i = 0; i < 4; i++) {
            int rr = wm * 64 + i * 16 + lm;
            a[i] = *(const bf16x8*)(As + rr * 32 + ((lh ^ ((rr >> 1) & 3)) * 8));
        }
#pragma unroll
        for (int j = 0; j < 4; j++) {
            int rr = wn * 64 + j * 16 + lm;
            bfr[j] = *(const bf16x8*)(Bs + rr * 32 + ((lh ^ ((rr >> 1) & 3)) * 8));
        }
#pragma unroll
        for (int i = 0; i < 4; i++)
#pragma unroll
            for (int j = 0; j < 4; j++)
                cacc[i][j] = __builtin_amdgcn_mfma_f32_16x16x32_bf16(a[i], bfr[j], cacc[i][j], 0, 0, 0);
        __syncthreads();
    }

    const int seg = bn >> 1;
    unsigned short* dst = (seg == 0) ? y0 : (seg == 1) ? y1 : y2;
    const int colbase = (bn * 128 + wn * 64) & 255;
#pragma unroll
    for (int i = 0; i < 4; i++) {
#pragma unroll
        for (int r = 0; r < 4; r++) {
            int grow = bm0 + wm * 64 + i * 16 + lh * 4 + r;
            if (grow < M_EDGES) {
#pragma unroll
                for (int j = 0; j < 4; j++) {
                    int col = colbase + j * 16 + lm;
                    dst[(size_t)grow * 256 + col] = f2bf(cacc[i][j][r]);
                }
            }
        }
    }
}

// ---------------------------------------------------------------------------
// CSR build
// ---------------------------------------------------------------------------
__global__ __launch_bounds__(256) void count_nodes(
    const int* __restrict__ en, int* __restrict__ cnt)
{
    int e = blockIdx.x * 256 + threadIdx.x;
    if (e < M_EDGES) {
        atomicAdd(&cnt[en[2 * e]], 1);
        atomicAdd(&cnt[en[2 * e + 1]], 1);
    }
}

__global__ __launch_bounds__(256) void count_tris(
    const int* __restrict__ te, int* __restrict__ cnt)
{
    int t = blockIdx.x * 256 + threadIdx.x;
    if (t < N_TRIS) {
#pragma unroll
        for (int k = 0; k < 3; k++) atomicAdd(&cnt[te[3 * t + k]], 1);
    }
}

__global__ __launch_bounds__(256) void scan_block(
    const int* __restrict__ cnt, int* __restrict__ off,
    int* __restrict__ partial, int n)
{
    __shared__ int s[256];
    int t = threadIdx.x;
    int gid = blockIdx.x * 256 + t;
    int v = (gid < n) ? cnt[gid] : 0;
    s[t] = v;
    __syncthreads();
    for (int o = 1; o < 256; o <<= 1) {
        int x = (t >= o) ? s[t - o] : 0;
        __syncthreads();
        s[t] += x;
        __syncthreads();
    }
    if (gid < n) off[gid] = s[t] - v;
    if (t == 255) partial[blockIdx.x] = s[255];
}

__global__ __launch_bounds__(1024) void scan_partial(int* __restrict__ partial, int nb)
{
    __shared__ int s[1024];
    int t = threadIdx.x;
    int v = (t < nb) ? partial[t] : 0;
    s[t] = v;
    __syncthreads();
    for (int o = 1; o < 1024; o <<= 1) {
        int x = (t >= o) ? s[t - o] : 0;
        __syncthreads();
        s[t] += x;
        __syncthreads();
    }
    if (t < nb) partial[t] = s[t] - v;
}

__global__ __launch_bounds__(256) void scan_add(
    int* __restrict__ off, int* __restrict__ cursor,
    const int* __restrict__ partial, int n, int total)
{
    int gid = blockIdx.x * 256 + threadIdx.x;
    if (gid == 0) off[n] = total;
    if (gid < n) {
        int o = off[gid] + partial[blockIdx.x];
        off[gid] = o;
        cursor[gid] = o;
    }
}

__global__ __launch_bounds__(256) void fill_nodes(
    const int* __restrict__ en, int* __restrict__ cursor, int* __restrict__ adj)
{
    int e = blockIdx.x * 256 + threadIdx.x;
    if (e < M_EDGES) {
        int u = en[2 * e], v = en[2 * e + 1];
        adj[atomicAdd(&cursor[u], 1)] = (e << 1);
        adj[atomicAdd(&cursor[v], 1)] = (e << 1) | 1;
    }
}

__global__ __launch_bounds__(256) void fill_tris(
    const int* __restrict__ te, const int* __restrict__ ts,
    int* __restrict__ cursor, int* __restrict__ adj)
{
    int t = blockIdx.x * 256 + threadIdx.x;
    if (t < N_TRIS) {
#pragma unroll
        for (int k = 0; k < 3; k++) {
            int e = te[3 * t + k];
            int neg = (ts[3 * t + k] < 0) ? 1 : 0;
            adj[atomicAdd(&cursor[e], 1)] = (t << 1) | neg;
        }
    }
}

// ---------------------------------------------------------------------------
// Fused gather pass A:
//   blocks [0, N_TRIS/4)          : w[t] = sum_k s_k * y2[e_k]
//   blocks [N_TRIS/4, +NN/4)      : z[n] = sum (+/-) y0[e]   (bf16 out)
// ---------------------------------------------------------------------------
#define WT_BLOCKS (N_TRIS / 4)
#define ZN_BLOCKS (NN_NODES / 4)

__global__ __launch_bounds__(256) void zw_fused(
    const unsigned short* __restrict__ y2,
    const int* __restrict__ te,
    const int* __restrict__ ts,
    unsigned short* __restrict__ w,
    const unsigned short* __restrict__ y0,
    const int* __restrict__ noff,
    const int* __restrict__ nadj,
    unsigned short* __restrict__ z)
{
    int lane = threadIdx.x & 63;
    int f = lane * 4;
    if (blockIdx.x < WT_BLOCKS) {
        int t = blockIdx.x * 4 + (threadIdx.x >> 6);
        int e0 = te[3 * t + 0], e1 = te[3 * t + 1], e2 = te[3 * t + 2];
        float s0 = (float)ts[3 * t + 0];
        float s1 = (float)ts[3 * t + 1];
        float s2 = (float)ts[3 * t + 2];
        ushort4 a4 = *(const ushort4*)(y2 + (size_t)e0 * 256 + f);
        ushort4 b4 = *(const ushort4*)(y2 + (size_t)e1 * 256 + f);
        ushort4 d4 = *(const ushort4*)(y2 + (size_t)e2 * 256 + f);
        ushort4 r;
        r.x = f2bf(s0 * bf2f(a4.x) + s1 * bf2f(b4.x) + s2 * bf2f(d4.x));
        r.y = f2bf(s0 * bf2f(a4.y) + s1 * bf2f(b4.y) + s2 * bf2f(d4.y));
        r.z = f2bf(s0 * bf2f(a4.z) + s1 * bf2f(b4.z) + s2 * bf2f(d4.z));
        r.w = f2bf(s0 * bf2f(a4.w) + s1 * bf2f(b4.w) + s2 * bf2f(d4.w));
        *(ushort4*)(w + (size_t)t * 256 + f) = r;
    } else {
        int n = (blockIdx.x - WT_BLOCKS) * 4 + (threadIdx.x >> 6);
        int beg = noff[n], end = noff[n + 1];
        float ax = 0.f, ay = 0.f, az = 0.f, aw = 0.f;
        int i = beg;
        for (; i + 1 < end; i += 2) {
            int ea = nadj[i], eb = nadj[i + 1];
            float sa = (ea & 1) ? 1.f : -1.f;
            float sb = (eb & 1) ? 1.f : -1.f;
            ushort4 va = *(const ushort4*)(y0 + (size_t)(ea >> 1) * 256 + f);
            ushort4 vb = *(const ushort4*)(y0 + (size_t)(eb >> 1) * 256 + f);
            ax += sa * bf2f(va.x) + sb * bf2f(vb.x);
            ay += sa * bf2f(va.y) + sb * bf2f(vb.y);
            az += sa * bf2f(va.z) + sb * bf2f(vb.z);
            aw += sa * bf2f(va.w) + sb * bf2f(vb.w);
        }
        if (i < end) {
            int ea = nadj[i];
            float sa = (ea & 1) ? 1.f : -1.f;
            ushort4 va = *(const ushort4*)(y0 + (size_t)(ea >> 1) * 256 + f);
            ax += sa * bf2f(va.x);
            ay += sa * bf2f(va.y);
            az += sa * bf2f(va.z);
            aw += sa * bf2f(va.w);
        }
        ushort4 r;
        r.x = f2bf(ax); r.y = f2bf(ay); r.z = f2bf(az); r.w = f2bf(aw);
        *(ushort4*)(z + (size_t)n * 256 + f) = r;
    }
}

// ---------------------------------------------------------------------------
// x_next[e] = relu( y1[e] + sum s*w[t] + z[v]-z[u] )
// ---------------------------------------------------------------------------
__global__ __launch_bounds__(256) void relu_fused(
    const unsigned short* __restrict__ y1,
    const unsigned short* __restrict__ w,
    const unsigned short* __restrict__ z,
    const int* __restrict__ en,
    const int* __restrict__ eoff,
    const int* __restrict__ eadj,
    unsigned short* __restrict__ xb)
{
    int e = blockIdx.x * 4 + (threadIdx.x >> 6);
    int lane = threadIdx.x & 63;
    int f = lane * 4;
    int u = en[2 * e], v = en[2 * e + 1];
    int beg = eoff[e], end = eoff[e + 1];
    ushort4 a4 = *(const ushort4*)(y1 + (size_t)e * 256 + f);
    ushort4 zv = *(const ushort4*)(z + (size_t)v * 256 + f);
    ushort4 zu = *(const ushort4*)(z + (size_t)u * 256 + f);
    float sx = bf2f(a4.x) + bf2f(zv.x) - bf2f(zu.x);
    float sy = bf2f(a4.y) + bf2f(zv.y) - bf2f(zu.y);
    float sz = bf2f(a4.z) + bf2f(zv.z) - bf2f(zu.z);
    float sw = bf2f(a4.w) + bf2f(zv.w) - bf2f(zu.w);
    int i = beg;
    for (; i + 1 < end; i += 2) {
        int ta = eadj[i], tb = eadj[i + 1];
        float sa = (ta & 1) ? -1.f : 1.f;
        float sb = (tb & 1) ? -1.f : 1.f;
        ushort4 wa = *(const ushort4*)(w + (size_t)(ta >> 1) * 256 + f);
        ushort4 wbv = *(const ushort4*)(w + (size_t)(tb >> 1) * 256 + f);
        sx += sa * bf2f(wa.x) + sb * bf2f(wbv.x);
        sy += sa * bf2f(wa.y) + sb * bf2f(wbv.y);
        sz += sa * bf2f(wa.z) + sb * bf2f(wbv.z);
        sw += sa * bf2f(wa.w) + sb * bf2f(wbv.w);
    }
    if (i < end) {
        int ta = eadj[i];
        float sa = (ta & 1) ? -1.f : 1.f;
        ushort4 wa = *(const ushort4*)(w + (size_t)(ta >> 1) * 256 + f);
        sx += sa * bf2f(wa.x);
        sy += sa * bf2f(wa.y);
        sz += sa * bf2f(wa.z);
        sw += sa * bf2f(wa.w);
    }
    ushort4 r;
    r.x = f2bf(fmaxf(sx, 0.f));
    r.y = f2bf(fmaxf(sy, 0.f));
    r.z = f2bf(fmaxf(sz, 0.f));
    r.w = f2bf(fmaxf(sw, 0.f));
    *(ushort4*)(xb + (size_t)e * 256 + f) = r;
}

// ---------------------------------------------------------------------------
// p[e] = x[e] . W0_L ; out[n] = sum (+/-) p[e]
// ---------------------------------------------------------------------------
__global__ __launch_bounds__(256) void dotp(
    const unsigned short* __restrict__ xb,
    const float* __restrict__ wl,
    float* __restrict__ p)
{
    int e = blockIdx.x * 4 + (threadIdx.x >> 6);
    int lane = threadIdx.x & 63;
    ushort4 xv = *(const ushort4*)(xb + (size_t)e * 256 + lane * 4);
    float4 wv = *(const float4*)(wl + lane * 4);
    float s = bf2f(xv.x) * wv.x + bf2f(xv.y) * wv.y +
              bf2f(xv.z) * wv.z + bf2f(xv.w) * wv.w;
#pragma unroll
    for (int off = 32; off > 0; off >>= 1)
        s += __shfl_down(s, off, 64);
    if (lane == 0) p[e] = s;
}

__global__ __launch_bounds__(256) void out_nodes(
    const float* __restrict__ p,
    const int* __restrict__ noff,
    const int* __restrict__ nadj,
    float* __restrict__ out)
{
    int n = blockIdx.x * 256 + threadIdx.x;
    if (n >= NN_NODES) return;
    int beg = noff[n], end = noff[n + 1];
    float s = 0.f;
    for (int i = beg; i < end; i++) {
        int ent = nadj[i];
        float sg = (ent & 1) ? 1.f : -1.f;
        s += sg * p[ent >> 1];
    }
    out[n] = s;
}

// ---------------------------------------------------------------------------
// Conversions
// ---------------------------------------------------------------------------
__global__ __launch_bounds__(256) void cvt_x(
    const float* __restrict__ x, unsigned short* __restrict__ xb)
{
    int idx = blockIdx.x * 256 + threadIdx.x;
    float4 v = *(const float4*)(x + (size_t)idx * 4);
    ushort4 r;
    r.x = f2bf(v.x); r.y = f2bf(v.y); r.z = f2bf(v.z); r.w = f2bf(v.w);
    *(ushort4*)(xb + (size_t)idx * 4) = r;
}

__global__ __launch_bounds__(256) void cvt_w(
    const float* __restrict__ W0, const float* __restrict__ W1,
    const float* __restrict__ W2, unsigned short* __restrict__ wt)
{
    int idx = blockIdx.x * 256 + threadIdx.x;
    int l = idx / (768 * 256);
    int rem = idx - l * (768 * 256);
    int n = rem >> 8;
    int k = rem & 255;
    const float* src;
    int nn;
    if (n < 256)      { src = W0; nn = n; }
    else if (n < 512) { src = W1; nn = n - 256; }
    else              { src = W2; nn = n - 512; }
    wt[idx] = f2bf(src[(size_t)l * 65536 + k * 256 + nn]);
}

extern "C" void kernel_launch(void* const* d_in, const int* in_sizes, int n_in,
                              void* d_out, int out_size, void* d_ws, size_t ws_size,
                              hipStream_t stream)
{
    const float* x0  = (const float*)d_in[0];
    const float* W0s = (const float*)d_in[1];
    const float* W1s = (const float*)d_in[2];
    const float* W2s = (const float*)d_in[3];
    const float* WL  = (const float*)d_in[4];
    const int*   en  = (const int*)d_in[5];
    const int*   te  = (const int*)d_in[6];
    const int*   ts  = (const int*)d_in[7];
    float* out = (float*)d_out;

    const size_t MF = (size_t)M_EDGES * F;
    unsigned short* xb = (unsigned short*)d_ws;        // MF
    unsigned short* y0 = xb + MF;                      // MF
    unsigned short* y1 = y0 + MF;                      // MF
    unsigned short* y2 = y1 + MF;                      // MF
    unsigned short* wt = y2 + MF;                      // 4*768*256
    unsigned short* wb = wt + (size_t)4 * 768 * 256;   // N_TRIS*256
    unsigned short* zb = wb + (size_t)N_TRIS * 256;    // NN*256
    float* p = (float*)(zb + (size_t)NN_NODES * 256);  // M f32
    int* noff = (int*)(p + M_EDGES);                   // NN+1
    int* ncur = noff + (NN_NODES + 1);                 // NN
    int* nadj = ncur + NN_NODES;                       // 2*M
    int* eoff = nadj + 2 * M_EDGES;                    // M+1
    int* ecur = eoff + (M_EDGES + 1);                  // M
    int* eadj = ecur + M_EDGES;                        // 3*N_TRIS
    int* part = eadj + 3 * N_TRIS;                     // 1024

    cvt_w<<<(4 * 768 * 256) / 256, 256, 0, stream>>>(W0s, W1s, W2s, wt);
    cvt_x<<<(int)(MF / 4 / 256), 256, 0, stream>>>(x0, xb);

    const int nbN = (NN_NODES + 255) / 256;
    const int nbE = (M_EDGES + 255) / 256;
    hipMemsetAsync(ncur, 0, NN_NODES * sizeof(int), stream);
    hipMemsetAsync(ecur, 0, M_EDGES * sizeof(int), stream);
    count_nodes<<<nbE, 256, 0, stream>>>(en, ncur);
    count_tris<<<(N_TRIS + 255) / 256, 256, 0, stream>>>(te, ecur);
    scan_block<<<nbN, 256, 0, stream>>>(ncur, noff, part, NN_NODES);
    scan_partial<<<1, 1024, 0, stream>>>(part, nbN);
    scan_add<<<nbN, 256, 0, stream>>>(noff, ncur, part, NN_NODES, 2 * M_EDGES);
    fill_nodes<<<nbE, 256, 0, stream>>>(en, ncur, nadj);
    scan_block<<<nbE, 256, 0, stream>>>(ecur, eoff, part, M_EDGES);
    scan_partial<<<1, 1024, 0, stream>>>(part, nbE);
    scan_add<<<nbE, 256, 0, stream>>>(eoff, ecur, part, M_EDGES, 3 * N_TRIS);
    fill_tris<<<(N_TRIS + 255) / 256, 256, 0, stream>>>(te, ts, ecur, eadj);

    // 8 XCDs * (NBM_PAD/8) bm-groups * 6 bn
    const int gemm_blocks = NBM_PAD * 6;   // 7056
    for (int l = 0; l < NLAYERS; l++) {
        gemm_mfma<<<gemm_blocks, 256, 0, stream>>>(
            xb, wt + (size_t)l * 768 * 256, y0, y1, y2);
        zw_fused<<<WT_BLOCKS + ZN_BLOCKS, 256, 0, stream>>>(
            y2, te, ts, wb, y0, noff, nadj, zb);
        relu_fused<<<M_EDGES / 4, 256, 0, stream>>>(y1, wb, zb, en, eoff, eadj, xb);
    }

    dotp<<<M_EDGES / 4, 256, 0, stream>>>(xb, WL, p);
    out_nodes<<<(NN_NODES + 255) / 256, 256, 0, stream>>>(p, noff, nadj, out);
}

// Round 7
// 1241.494 us; speedup vs baseline: 1.3658x; 1.1505x over previous
//
#include <hip/hip_runtime.h>

#define M_EDGES 150000
#define NN_NODES 50000
#define N_TRIS  100000
#define F 256
#define NLAYERS 4

// unified GEMM: virtual A = [x (150k) ; s (50k) ; q (100k)], 256 cols each
#define T0 1172                  // ceil(150000/128)
#define T1 391                   // ceil(50000/128)
#define T2 782                   // ceil(100000/128)
#define NTILES (T0 + T1 + T2)    // 2345
#define NT_PAD 2352              // 8 * ceil(NTILES/8)

typedef __attribute__((ext_vector_type(8))) __bf16 bf16x8;
typedef __attribute__((ext_vector_type(4))) float f32x4;

__device__ inline unsigned short f2bf(float f) {
    unsigned int u = __float_as_uint(f);
    u += 0x7fff + ((u >> 16) & 1);
    return (unsigned short)(u >> 16);
}
__device__ inline float bf2f(unsigned short h) {
    return __uint_as_float(((unsigned int)h) << 16);
}

__device__ inline void async16(const void* g, void* l) {
    __builtin_amdgcn_global_load_lds(
        (const __attribute__((address_space(1))) void*)g,
        (__attribute__((address_space(3))) void*)l, 16, 0, 0);
}

// ---------------------------------------------------------------------------
// Unified bf16 MFMA GEMM over 3 row-segments:
//   seg0: y1 = x @ W1   (150000 rows)
//   seg1: z  = s @ W0   (50000 rows)   [B1 pushed through W0]
//   seg2: w  = q @ W2   (100000 rows)  [B2^T pushed through W2]
// Weights wt layout: [seg][n][k] (n-major, 256x256 per seg).
// XCD swizzle: xcd=b&7, c=b>>3, tile=(c/2)*8+xcd, bn=c%2 -> both bn blocks of
// a tile share an XCD L2 (r6: FETCH 227->40MB with this scheme at nb=6).
// XOR-swizzled LDS (conflict-free, r4-verified). Epilogue uses SWAPPED mfma
// operands: mfma(b,a,c) -> lane holds 4 consecutive output cols -> ushort4
// stores (16 per thread instead of 64 scalar shorts).
// ---------------------------------------------------------------------------
__global__ __launch_bounds__(256) void gemm_mfma(
    const unsigned short* __restrict__ xb,
    const unsigned short* __restrict__ sb,
    const unsigned short* __restrict__ qb,
    const unsigned short* __restrict__ wt,
    unsigned short* __restrict__ y1,
    unsigned short* __restrict__ zb,
    unsigned short* __restrict__ wb)
{
    __shared__ unsigned short As[128 * 32];
    __shared__ unsigned short Bs[128 * 32];

    const int b    = blockIdx.x;
    const int xcd  = b & 7;
    const int c    = b >> 3;
    const int tile = (c >> 1) * 8 + xcd;
    const int bn   = c & 1;
    if (tile >= NTILES) return;

    int seg, tloc;
    if (tile < T0)            { seg = 0; tloc = tile; }
    else if (tile < T0 + T1)  { seg = 1; tloc = tile - T0; }
    else                      { seg = 2; tloc = tile - T0 - T1; }
    const unsigned short* Asrc = (seg == 0) ? xb : (seg == 1) ? sb : qb;
    const int nrows = (seg == 0) ? M_EDGES : (seg == 1) ? NN_NODES : N_TRIS;
    const unsigned short* wsel = wt + seg * 65536;
    unsigned short* dst = (seg == 0) ? y1 : (seg == 1) ? zb : wb;

    const int tid  = threadIdx.x;
    const int bm0  = tloc * 128;
    const int wid  = tid >> 6;
    const int lane = tid & 63;
    const int lm   = lane & 15;
    const int lh   = lane >> 4;
    const int wm   = wid >> 1;
    const int wn   = wid & 1;
    const int wbase = tid & ~63;

    f32x4 cacc[4][4];
#pragma unroll
    for (int i = 0; i < 4; i++)
#pragma unroll
        for (int j = 0; j < 4; j++) cacc[i][j] = (f32x4){0.f, 0.f, 0.f, 0.f};

    for (int k0 = 0; k0 < 256; k0 += 32) {
#pragma unroll
        for (int s = 0; s < 2; s++) {
            int i   = s * 256 + tid;                 // slot = physical granule
            int row = i >> 2;
            int g   = (i & 3) ^ ((row >> 1) & 3);    // logical k-granule
            int gr  = bm0 + row;
            if (gr > nrows - 1) gr = nrows - 1;
            async16(Asrc + (size_t)gr * 256 + k0 + g * 8,
                    As + (size_t)(s * 256 + wbase) * 8);
            int nrow = bn * 128 + row;
            async16(wsel + (size_t)nrow * 256 + k0 + g * 8,
                    Bs + (size_t)(s * 256 + wbase) * 8);
        }
        asm volatile("s_waitcnt vmcnt(0)" ::: "memory");
        __syncthreads();

        bf16x8 a[4], bfr[4];
#pragma unroll
        for (int i = 0; i < 4; i++) {
            int rr = wm * 64 + i * 16 + lm;
            a[i] = *(const bf16x8*)(As + rr * 32 + ((lh ^ ((rr >> 1) & 3)) * 8));
        }
#pragma unroll
        for (int j = 0; j < 4; j++) {
            int rr = wn * 64 + j * 16 + lm;
            bfr[j] = *(const bf16x8*)(Bs + rr * 32 + ((lh ^ ((rr >> 1) & 3)) * 8));
        }
        // swapped operands: result lane holds row m=lm, cols n=lh*4+reg
#pragma unroll
        for (int i = 0; i < 4; i++)
#pragma unroll
            for (int j = 0; j < 4; j++)
                cacc[i][j] = __builtin_amdgcn_mfma_f32_16x16x32_bf16(bfr[j], a[i], cacc[i][j], 0, 0, 0);
        __syncthreads();
    }

#pragma unroll
    for (int i = 0; i < 4; i++) {
        int grow = bm0 + wm * 64 + i * 16 + lm;
        if (grow < nrows) {
#pragma unroll
            for (int j = 0; j < 4; j++) {
                int col = bn * 128 + wn * 64 + j * 16 + lh * 4;
                ushort4 r;
                r.x = f2bf(cacc[i][j][0]);
                r.y = f2bf(cacc[i][j][1]);
                r.z = f2bf(cacc[i][j][2]);
                r.w = f2bf(cacc[i][j][3]);
                *(ushort4*)(dst + (size_t)grow * 256 + col) = r;
            }
        }
    }
}

// ---------------------------------------------------------------------------
// CSR build
// ---------------------------------------------------------------------------
__global__ __launch_bounds__(256) void count_nodes(
    const int* __restrict__ en, int* __restrict__ cnt)
{
    int e = blockIdx.x * 256 + threadIdx.x;
    if (e < M_EDGES) {
        atomicAdd(&cnt[en[2 * e]], 1);
        atomicAdd(&cnt[en[2 * e + 1]], 1);
    }
}

__global__ __launch_bounds__(256) void count_tris(
    const int* __restrict__ te, int* __restrict__ cnt)
{
    int t = blockIdx.x * 256 + threadIdx.x;
    if (t < N_TRIS) {
#pragma unroll
        for (int k = 0; k < 3; k++) atomicAdd(&cnt[te[3 * t + k]], 1);
    }
}

__global__ __launch_bounds__(256) void scan_block(
    const int* __restrict__ cnt, int* __restrict__ off,
    int* __restrict__ partial, int n)
{
    __shared__ int s[256];
    int t = threadIdx.x;
    int gid = blockIdx.x * 256 + t;
    int v = (gid < n) ? cnt[gid] : 0;
    s[t] = v;
    __syncthreads();
    for (int o = 1; o < 256; o <<= 1) {
        int x = (t >= o) ? s[t - o] : 0;
        __syncthreads();
        s[t] += x;
        __syncthreads();
    }
    if (gid < n) off[gid] = s[t] - v;
    if (t == 255) partial[blockIdx.x] = s[255];
}

__global__ __launch_bounds__(1024) void scan_partial(int* __restrict__ partial, int nb)
{
    __shared__ int s[1024];
    int t = threadIdx.x;
    int v = (t < nb) ? partial[t] : 0;
    s[t] = v;
    __syncthreads();
    for (int o = 1; o < 1024; o <<= 1) {
        int x = (t >= o) ? s[t - o] : 0;
        __syncthreads();
        s[t] += x;
        __syncthreads();
    }
    if (t < nb) partial[t] = s[t] - v;
}

__global__ __launch_bounds__(256) void scan_add(
    int* __restrict__ off, int* __restrict__ cursor,
    const int* __restrict__ partial, int n, int total)
{
    int gid = blockIdx.x * 256 + threadIdx.x;
    if (gid == 0) off[n] = total;
    if (gid < n) {
        int o = off[gid] + partial[blockIdx.x];
        off[gid] = o;
        cursor[gid] = o;
    }
}

__global__ __launch_bounds__(256) void fill_nodes(
    const int* __restrict__ en, int* __restrict__ cursor, int* __restrict__ adj)
{
    int e = blockIdx.x * 256 + threadIdx.x;
    if (e < M_EDGES) {
        int u = en[2 * e], v = en[2 * e + 1];
        adj[atomicAdd(&cursor[u], 1)] = (e << 1);        // u endpoint: minus
        adj[atomicAdd(&cursor[v], 1)] = (e << 1) | 1;    // v endpoint: plus
    }
}

__global__ __launch_bounds__(256) void fill_tris(
    const int* __restrict__ te, const int* __restrict__ ts,
    int* __restrict__ cursor, int* __restrict__ adj)
{
    int t = blockIdx.x * 256 + threadIdx.x;
    if (t < N_TRIS) {
#pragma unroll
        for (int k = 0; k < 3; k++) {
            int e = te[3 * t + k];
            int neg = (ts[3 * t + k] < 0) ? 1 : 0;
            adj[atomicAdd(&cursor[e], 1)] = (t << 1) | neg;
        }
    }
}

// ---------------------------------------------------------------------------
// Aggregation pass (pre-GEMM):
//   blocks [0, ZN_BLOCKS)        : s[n] = sum (+/-) x[e]   (node CSR)
//   blocks [ZN_BLOCKS, +WT)      : q[t] = sum s_k * x[e_k] (tri direct)
// ---------------------------------------------------------------------------
#define ZN_BLOCKS (NN_NODES / 4)
#define WT_BLOCKS (N_TRIS / 4)

__global__ __launch_bounds__(256) void agg_fused(
    const unsigned short* __restrict__ xb,
    const int* __restrict__ noff,
    const int* __restrict__ nadj,
    unsigned short* __restrict__ sbuf,
    const int* __restrict__ te,
    const int* __restrict__ ts,
    unsigned short* __restrict__ qbuf)
{
    int lane = threadIdx.x & 63;
    int f = lane * 4;
    if (blockIdx.x < ZN_BLOCKS) {
        int n = blockIdx.x * 4 + (threadIdx.x >> 6);
        int beg = noff[n], end = noff[n + 1];
        float ax = 0.f, ay = 0.f, az = 0.f, aw = 0.f;
        int i = beg;
        for (; i + 1 < end; i += 2) {
            int ea = nadj[i], eb = nadj[i + 1];
            float sa = (ea & 1) ? 1.f : -1.f;
            float sgb = (eb & 1) ? 1.f : -1.f;
            ushort4 va = *(const ushort4*)(xb + (size_t)(ea >> 1) * 256 + f);
            ushort4 vb = *(const ushort4*)(xb + (size_t)(eb >> 1) * 256 + f);
            ax += sa * bf2f(va.x) + sgb * bf2f(vb.x);
            ay += sa * bf2f(va.y) + sgb * bf2f(vb.y);
            az += sa * bf2f(va.z) + sgb * bf2f(vb.z);
            aw += sa * bf2f(va.w) + sgb * bf2f(vb.w);
        }
        if (i < end) {
            int ea = nadj[i];
            float sa = (ea & 1) ? 1.f : -1.f;
            ushort4 va = *(const ushort4*)(xb + (size_t)(ea >> 1) * 256 + f);
            ax += sa * bf2f(va.x);
            ay += sa * bf2f(va.y);
            az += sa * bf2f(va.z);
            aw += sa * bf2f(va.w);
        }
        ushort4 r;
        r.x = f2bf(ax); r.y = f2bf(ay); r.z = f2bf(az); r.w = f2bf(aw);
        *(ushort4*)(sbuf + (size_t)n * 256 + f) = r;
    } else {
        int t = (blockIdx.x - ZN_BLOCKS) * 4 + (threadIdx.x >> 6);
        int e0 = te[3 * t + 0], e1 = te[3 * t + 1], e2 = te[3 * t + 2];
        float s0 = (float)ts[3 * t + 0];
        float s1 = (float)ts[3 * t + 1];
        float s2 = (float)ts[3 * t + 2];
        ushort4 a4 = *(const ushort4*)(xb + (size_t)e0 * 256 + f);
        ushort4 b4 = *(const ushort4*)(xb + (size_t)e1 * 256 + f);
        ushort4 d4 = *(const ushort4*)(xb + (size_t)e2 * 256 + f);
        ushort4 r;
        r.x = f2bf(s0 * bf2f(a4.x) + s1 * bf2f(b4.x) + s2 * bf2f(d4.x));
        r.y = f2bf(s0 * bf2f(a4.y) + s1 * bf2f(b4.y) + s2 * bf2f(d4.y));
        r.z = f2bf(s0 * bf2f(a4.z) + s1 * bf2f(b4.z) + s2 * bf2f(d4.z));
        r.w = f2bf(s0 * bf2f(a4.w) + s1 * bf2f(b4.w) + s2 * bf2f(d4.w));
        *(ushort4*)(qbuf + (size_t)t * 256 + f) = r;
    }
}

// ---------------------------------------------------------------------------
// x_next[e] = relu( y1[e] + sum s*w[t] + z[v]-z[u] )
// ---------------------------------------------------------------------------
__global__ __launch_bounds__(256) void relu_fused(
    const unsigned short* __restrict__ y1,
    const unsigned short* __restrict__ w,
    const unsigned short* __restrict__ z,
    const int* __restrict__ en,
    const int* __restrict__ eoff,
    const int* __restrict__ eadj,
    unsigned short* __restrict__ xb)
{
    int e = blockIdx.x * 4 + (threadIdx.x >> 6);
    int lane = threadIdx.x & 63;
    int f = lane * 4;
    int u = en[2 * e], v = en[2 * e + 1];
    int beg = eoff[e], end = eoff[e + 1];
    ushort4 a4 = *(const ushort4*)(y1 + (size_t)e * 256 + f);
    ushort4 zv = *(const ushort4*)(z + (size_t)v * 256 + f);
    ushort4 zu = *(const ushort4*)(z + (size_t)u * 256 + f);
    float sx = bf2f(a4.x) + bf2f(zv.x) - bf2f(zu.x);
    float sy = bf2f(a4.y) + bf2f(zv.y) - bf2f(zu.y);
    float sz = bf2f(a4.z) + bf2f(zv.z) - bf2f(zu.z);
    float sw = bf2f(a4.w) + bf2f(zv.w) - bf2f(zu.w);
    int i = beg;
    for (; i + 1 < end; i += 2) {
        int ta = eadj[i], tb = eadj[i + 1];
        float sa = (ta & 1) ? -1.f : 1.f;
        float sgb = (tb & 1) ? -1.f : 1.f;
        ushort4 wa = *(const ushort4*)(w + (size_t)(ta >> 1) * 256 + f);
        ushort4 wbv = *(const ushort4*)(w + (size_t)(tb >> 1) * 256 + f);
        sx += sa * bf2f(wa.x) + sgb * bf2f(wbv.x);
        sy += sa * bf2f(wa.y) + sgb * bf2f(wbv.y);
        sz += sa * bf2f(wa.z) + sgb * bf2f(wbv.z);
        sw += sa * bf2f(wa.w) + sgb * bf2f(wbv.w);
    }
    if (i < end) {
        int ta = eadj[i];
        float sa = (ta & 1) ? -1.f : 1.f;
        ushort4 wa = *(const ushort4*)(w + (size_t)(ta >> 1) * 256 + f);
        sx += sa * bf2f(wa.x);
        sy += sa * bf2f(wa.y);
        sz += sa * bf2f(wa.z);
        sw += sa * bf2f(wa.w);
    }
    ushort4 r;
    r.x = f2bf(fmaxf(sx, 0.f));
    r.y = f2bf(fmaxf(sy, 0.f));
    r.z = f2bf(fmaxf(sz, 0.f));
    r.w = f2bf(fmaxf(sw, 0.f));
    *(ushort4*)(xb + (size_t)e * 256 + f) = r;
}

// ---------------------------------------------------------------------------
// p[e] = x[e] . W0_L ; out[n] = sum (+/-) p[e]
// ---------------------------------------------------------------------------
__global__ __launch_bounds__(256) void dotp(
    const unsigned short* __restrict__ xb,
    const float* __restrict__ wl,
    float* __restrict__ p)
{
    int e = blockIdx.x * 4 + (threadIdx.x >> 6);
    int lane = threadIdx.x & 63;
    ushort4 xv = *(const ushort4*)(xb + (size_t)e * 256 + lane * 4);
    float4 wv = *(const float4*)(wl + lane * 4);
    float s = bf2f(xv.x) * wv.x + bf2f(xv.y) * wv.y +
              bf2f(xv.z) * wv.z + bf2f(xv.w) * wv.w;
#pragma unroll
    for (int off = 32; off > 0; off >>= 1)
        s += __shfl_down(s, off, 64);
    if (lane == 0) p[e] = s;
}

__global__ __launch_bounds__(256) void out_nodes(
    const float* __restrict__ p,
    const int* __restrict__ noff,
    const int* __restrict__ nadj,
    float* __restrict__ out)
{
    int n = blockIdx.x * 256 + threadIdx.x;
    if (n >= NN_NODES) return;
    int beg = noff[n], end = noff[n + 1];
    float s = 0.f;
    for (int i = beg; i < end; i++) {
        int ent = nadj[i];
        float sg = (ent & 1) ? 1.f : -1.f;
        s += sg * p[ent >> 1];
    }
    out[n] = s;
}

// ---------------------------------------------------------------------------
// Conversions
// ---------------------------------------------------------------------------
__global__ __launch_bounds__(256) void cvt_x(
    const float* __restrict__ x, unsigned short* __restrict__ xb)
{
    int idx = blockIdx.x * 256 + threadIdx.x;
    float4 v = *(const float4*)(x + (size_t)idx * 4);
    ushort4 r;
    r.x = f2bf(v.x); r.y = f2bf(v.y); r.z = f2bf(v.z); r.w = f2bf(v.w);
    *(ushort4*)(xb + (size_t)idx * 4) = r;
}

// wt[l][seg][n][k], seg order = (W1, W0, W2) matching GEMM segments
__global__ __launch_bounds__(256) void cvt_w(
    const float* __restrict__ W0, const float* __restrict__ W1,
    const float* __restrict__ W2, unsigned short* __restrict__ wt)
{
    int idx = blockIdx.x * 256 + threadIdx.x;   // 4*3*65536 total
    int l = idx / (3 * 65536);
    int rem = idx - l * (3 * 65536);
    int seg = rem >> 16;
    int n = (rem >> 8) & 255;
    int k = rem & 255;
    const float* src = (seg == 0) ? W1 : (seg == 1) ? W0 : W2;
    wt[idx] = f2bf(src[(size_t)l * 65536 + k * 256 + n]);
}

extern "C" void kernel_launch(void* const* d_in, const int* in_sizes, int n_in,
                              void* d_out, int out_size, void* d_ws, size_t ws_size,
                              hipStream_t stream)
{
    const float* x0  = (const float*)d_in[0];
    const float* W0s = (const float*)d_in[1];
    const float* W1s = (const float*)d_in[2];
    const float* W2s = (const float*)d_in[3];
    const float* WL  = (const float*)d_in[4];
    const int*   en  = (const int*)d_in[5];
    const int*   te  = (const int*)d_in[6];
    const int*   ts  = (const int*)d_in[7];
    float* out = (float*)d_out;

    const size_t MF = (size_t)M_EDGES * F;
    unsigned short* xb = (unsigned short*)d_ws;          // MF
    unsigned short* y1 = xb + MF;                        // MF
    unsigned short* sbuf = y1 + MF;                      // NN*256
    unsigned short* qbuf = sbuf + (size_t)NN_NODES * 256;// N_TRIS*256
    unsigned short* wt = qbuf + (size_t)N_TRIS * 256;    // 4*3*65536
    unsigned short* wb = wt + (size_t)4 * 3 * 65536;     // N_TRIS*256
    unsigned short* zb = wb + (size_t)N_TRIS * 256;      // NN*256
    float* p = (float*)(zb + (size_t)NN_NODES * 256);    // M f32
    int* noff = (int*)(p + M_EDGES);                     // NN+1
    int* ncur = noff + (NN_NODES + 1);                   // NN
    int* nadj = ncur + NN_NODES;                         // 2*M
    int* eoff = nadj + 2 * M_EDGES;                      // M+1
    int* ecur = eoff + (M_EDGES + 1);                    // M
    int* eadj = ecur + M_EDGES;                          // 3*N_TRIS
    int* part = eadj + 3 * N_TRIS;                       // 1024

    cvt_w<<<(4 * 3 * 65536) / 256, 256, 0, stream>>>(W0s, W1s, W2s, wt);
    cvt_x<<<(int)(MF / 4 / 256), 256, 0, stream>>>(x0, xb);

    const int nbN = (NN_NODES + 255) / 256;
    const int nbE = (M_EDGES + 255) / 256;
    hipMemsetAsync(ncur, 0, NN_NODES * sizeof(int), stream);
    hipMemsetAsync(ecur, 0, M_EDGES * sizeof(int), stream);
    count_nodes<<<nbE, 256, 0, stream>>>(en, ncur);
    count_tris<<<(N_TRIS + 255) / 256, 256, 0, stream>>>(te, ecur);
    scan_block<<<nbN, 256, 0, stream>>>(ncur, noff, part, NN_NODES);
    scan_partial<<<1, 1024, 0, stream>>>(part, nbN);
    scan_add<<<nbN, 256, 0, stream>>>(noff, ncur, part, NN_NODES, 2 * M_EDGES);
    fill_nodes<<<nbE, 256, 0, stream>>>(en, ncur, nadj);
    scan_block<<<nbE, 256, 0, stream>>>(ecur, eoff, part, M_EDGES);
    scan_partial<<<1, 1024, 0, stream>>>(part, nbE);
    scan_add<<<nbE, 256, 0, stream>>>(eoff, ecur, part, M_EDGES, 3 * N_TRIS);
    fill_tris<<<(N_TRIS + 255) / 256, 256, 0, stream>>>(te, ts, ecur, eadj);

    const int gemm_blocks = NT_PAD * 2;   // 4704
    for (int l = 0; l < NLAYERS; l++) {
        agg_fused<<<ZN_BLOCKS + WT_BLOCKS, 256, 0, stream>>>(
            xb, noff, nadj, sbuf, te, ts, qbuf);
        gemm_mfma<<<gemm_blocks, 256, 0, stream>>>(
            xb, sbuf, qbuf, wt + (size_t)l * 3 * 65536, y1, zb, wb);
        relu_fused<<<M_EDGES / 4, 256, 0, stream>>>(y1, wb, zb, en, eoff, eadj, xb);
    }

    dotp<<<M_EDGES / 4, 256, 0, stream>>>(xb, WL, p);
    out_nodes<<<(NN_NODES + 255) / 256, 256, 0, stream>>>(p, noff, nadj, out);
}